// Round 3
// baseline (265.476 us; speedup 1.0000x reference)
//
#include <hip/hip_runtime.h>
#include <cstdint>
#include <cstddef>

// Problem constants (B=4, T=2048, C=1024, H=16, D=64). I/O dtype: fp32.
#define Bsz   4
#define Tsz   2048
#define Csz   1024
#define Hn    16
#define Dh    64
#define Mrows 8192        // B*T
#define KD    1024        // K dim of both GEMMs (= C)

#define NEG_BIG (-1.0e30f)   // finite mask sentinel: exp2(NEG_BIG) flushes to 0
#define SCL2  0.18033688011112042f  // (1/sqrt(64)) * log2(e): folded into Q at
// the QKV epilogue. p = exp2(s) directly; uniform 2^bias cancels in sum(pv)/sum(p).

typedef unsigned short u16;
typedef __bf16  bf16x8 __attribute__((ext_vector_type(8)));
typedef __bf16  bf16x2 __attribute__((ext_vector_type(2)));
typedef float   f32x4  __attribute__((ext_vector_type(4)));
typedef unsigned int u32x4 __attribute__((ext_vector_type(4)));

// Raw barrier + compiler memory fences on both sides (no implicit vmcnt(0)
// drain -- that drain is the structural stall of __syncthreads pipelines).
#define BARRIER() do { asm volatile("" ::: "memory");                          \
                       __builtin_amdgcn_s_barrier();                           \
                       asm volatile("" ::: "memory"); } while (0)

__device__ __forceinline__ u16 f2bf(float f) {
  union { float f; unsigned int i; } v; v.f = f;
  unsigned int u = v.i;
  return (u16)((u + 0x7fffu + ((u >> 16) & 1u)) >> 16);   // RNE
}
// Pack two f32 -> two bf16 in one uint (low = a, high = b), RNE.
__device__ __forceinline__ unsigned int pack2bf(float a, float b) {
#if __has_builtin(__builtin_amdgcn_cvt_pk_bf16_f32)
  union { bf16x2 h; unsigned int u; } cv;
  cv.h = __builtin_amdgcn_cvt_pk_bf16_f32(a, b);
  return cv.u;
#else
  return (unsigned int)f2bf(a) | ((unsigned int)f2bf(b) << 16);
#endif
}
// Pack two f32 -> two bf16 by TRUNCATION via one v_perm_b32 (positive P only).
__device__ __forceinline__ unsigned int pack2bf_trunc(float lo, float hi) {
  return __builtin_amdgcn_perm(__builtin_bit_cast(unsigned int, hi),
                               __builtin_bit_cast(unsigned int, lo),
                               0x07060302u);
}
__device__ __forceinline__ float fast_exp2(float x) {
#if __has_builtin(__builtin_amdgcn_exp2f)
  return __builtin_amdgcn_exp2f(x);
#else
  return exp2f(x);
#endif
}

// ---------------------------------------------------------------------------
// Fused preprocessing (ONE launch): region 0 converts x to bf16; regions 1/2
// transpose+convert W_attn / W_proj.
// ---------------------------------------------------------------------------
#define CVT_BLKS  (Mrows * Csz / 4 / 256)   // 8192
#define TRA_BLKS  (48 * 16)                 // W_attn: [1024][3072] -> [3072][1024]
#define TRP_BLKS  (16 * 16)                 // W_proj: [1024][1024] -> [1024][1024]

__global__ __launch_bounds__(256)
void prep(const float* __restrict__ x, u16* __restrict__ xbf,
          const float* __restrict__ Wa, u16* __restrict__ WTa,
          const float* __restrict__ Wp, u16* __restrict__ WTp) {
  __shared__ u16 tile[64][65];
  int bid = blockIdx.x;
  const int tid = threadIdx.x;
  if (bid < CVT_BLKS) {
    const int i = bid * 256 + tid;
    const float4 v = ((const float4*)x)[i];
    uint2 o;
    o.x = pack2bf(v.x, v.y);
    o.y = pack2bf(v.z, v.w);
    ((uint2*)xbf)[i] = o;
    return;
  }
  bid -= CVT_BLKS;
  const float* in; u16* out; int cols, bx, by;
  if (bid < TRA_BLKS) {
    in = Wa; out = WTa; cols = 3 * Csz; bx = bid % 48; by = bid / 48;
  } else {
    bid -= TRA_BLKS;
    in = Wp; out = WTp; cols = Csz; bx = bid & 15; by = bid >> 4;
  }
  const int tc = bx * 64, tr = by * 64;
  const int xx = tid & 63, y0 = tid >> 6;
#pragma unroll
  for (int yy = 0; yy < 64; yy += 4) {
    int r = yy + y0;
    tile[r][xx] = f2bf(in[(size_t)(tr + r) * cols + tc + xx]);
  }
  __syncthreads();
#pragma unroll
  for (int yy = 0; yy < 64; yy += 4) {
    int r = yy + y0;
    out[(size_t)(tc + r) * Csz + tr + xx] = tile[xx][r];
  }
}

// ---------------------------------------------------------------------------
// GEMM C[M,N] = A[M,K] * BT[N,K]^T + bias[N], bf16 in, fp32 acc.
// V3 (m201 geometry): 256x256 tile, BK=64, 512 threads = 8 waves (2M x 4N),
// per-wave output 128x64 -> 44 FLOP per LDS byte (vs 32 at 64x64 wave tiles;
// the 128^2 structure was LDS-BW-bound at 27% MfmaUtil both prior rounds).
// Double-buffered LDS (128 KiB), DMA staging via global_load_lds with
// pre-swizzled source (chunk ^= row&7; measured 0 bank conflicts), A staged
// at phase 0 / B staged mid-tile, counted s_waitcnt vmcnt(4) (0 only on the
// last tile), raw barriers, setprio(1) around MFMA, bijective XCD swizzle.
// Two compute phases per K-tile (ks=0, ks=1): 12 ds_read_b128 + 32 MFMA each.
// MODE 0: QKV epilogue -> q/k scatter [bh][t][d]; Q PRE-SCALED by SCL2;
//         V scatter TRANSPOSED [bh][d][t] (packed 8B stores).
// MODE 1: plain epilogue -> fp32 fout[row*N + col].
// ---------------------------------------------------------------------------
template<int MODE>
__global__ __launch_bounds__(512, 2)
void gemm_bt(const u16* __restrict__ A, const u16* __restrict__ BT,
             const float* __restrict__ bias, u16* __restrict__ o0,
             u16* __restrict__ o1, u16* __restrict__ o2,
             float* __restrict__ fout, int N) {
  __shared__ u16 lsA[2][256 * 64];   // [buf][row][64], chunk-swizzled content
  __shared__ u16 lsB[2][256 * 64];
  const int tid  = threadIdx.x;
  const int lane = tid & 63;
  const int wid  = tid >> 6;               // 0..7
  const int wm   = wid >> 2, wn = wid & 3; // wave tile: 128(M) x 64(N)
  const int quad = lane >> 4, l15 = lane & 15;
  const int rswz = l15 & 7;                // read-side XOR (16B-chunk units)

  // Bijective XCD-aware swizzle (grid sizes 384 / 128, both % 8 == 0).
  int bx, by;
  {
    const int nwg  = gridDim.x * gridDim.y;
    const int orig = (int)blockIdx.y * gridDim.x + (int)blockIdx.x;
    const int cpx  = nwg >> 3;
    const int swz  = (orig & 7) * cpx + (orig >> 3);
    bx = swz % gridDim.x; by = swz / gridDim.x;
  }
  const int m0 = by * 256, n0 = bx * 256;

  f32x4 acc[8][4];
#pragma unroll
  for (int i = 0; i < 8; ++i)
#pragma unroll
    for (int j = 0; j < 4; ++j) acc[i][j] = (f32x4){0.f, 0.f, 0.f, 0.f};

  // Staging: wave w DMAs rows [w*32, w*32+32) of A and of B per K-tile
  // (4 x 1KB instrs each). Lane l covers row +(l>>3), source chunk
  // (l&7)^(l>>3) -- inverse swizzle, so LDS[r][c] = G[r][c ^ (r&7)] with a
  // LINEAR global_load_lds dest.
  const int srow   = lane >> 3;
  const int schunk = (lane & 7) ^ srow;
  const u16* gA = A  + (size_t)(m0 + wid * 32 + srow) * KD + schunk * 8;
  const u16* gB = BT + (size_t)(n0 + wid * 32 + srow) * KD + schunk * 8;

#if __has_builtin(__builtin_amdgcn_global_load_lds)
#define GSTAGE_A(t_, bb_) do {                                                 \
    _Pragma("unroll")                                                          \
    for (int i_ = 0; i_ < 4; ++i_)                                             \
      __builtin_amdgcn_global_load_lds(                                        \
        (const __attribute__((address_space(1))) void*)(gA + (size_t)i_ * 8 * KD + (t_) * 64), \
        (__attribute__((address_space(3))) void*)(&lsA[bb_][(wid * 32 + i_ * 8) * 64]), 16, 0, 0); \
  } while (0)
#define GSTAGE_B(t_, bb_) do {                                                 \
    _Pragma("unroll")                                                          \
    for (int i_ = 0; i_ < 4; ++i_)                                             \
      __builtin_amdgcn_global_load_lds(                                        \
        (const __attribute__((address_space(1))) void*)(gB + (size_t)i_ * 8 * KD + (t_) * 64), \
        (__attribute__((address_space(3))) void*)(&lsB[bb_][(wid * 32 + i_ * 8) * 64]), 16, 0, 0); \
  } while (0)
#else
#define GSTAGE_A(t_, bb_) do {                                                 \
    _Pragma("unroll")                                                          \
    for (int cc_ = 0; cc_ < 4; ++cc_) {                                        \
      const int c_ = tid + cc_ * 512;                                          \
      const int rr_ = c_ >> 3, off_ = c_ & 7;                                  \
      const int dc_ = (off_ ^ (rr_ & 7)) << 3;                                 \
      *(uint4*)&lsA[bb_][rr_ * 64 + dc_] =                                     \
          *(const uint4*)&A[(size_t)(m0 + rr_) * KD + (t_) * 64 + off_ * 8];   \
    }                                                                          \
  } while (0)
#define GSTAGE_B(t_, bb_) do {                                                 \
    _Pragma("unroll")                                                          \
    for (int cc_ = 0; cc_ < 4; ++cc_) {                                        \
      const int c_ = tid + cc_ * 512;                                          \
      const int rr_ = c_ >> 3, off_ = c_ & 7;                                  \
      const int dc_ = (off_ ^ (rr_ & 7)) << 3;                                 \
      *(uint4*)&lsB[bb_][rr_ * 64 + dc_] =                                     \
          *(const uint4*)&BT[(size_t)(n0 + rr_) * KD + (t_) * 64 + off_ * 8];  \
    }                                                                          \
  } while (0)
#endif

  GSTAGE_A(0, 0);
  GSTAGE_B(0, 0);                 // 8 DMA instrs in flight
  const int KT = KD / 64;         // 16
  for (int t = 0; t < KT; ++t) {
    const int cur = t & 1;
    if (t < KT - 1) {
      GSTAGE_A(t + 1, cur ^ 1);   // prefetch next A half-pair into other buf
      asm volatile("s_waitcnt vmcnt(4)" ::: "memory");  // tile t landed; 4 fly
    } else {
      asm volatile("s_waitcnt vmcnt(0)" ::: "memory");
    }
    BARRIER();                    // all waves' slices of buf[cur] visible

    // ---- phase 0: ks = 0 ----
    bf16x8 bfv[4], af[8];
#pragma unroll
    for (int n = 0; n < 4; ++n)
      bfv[n] = *(const bf16x8*)
          &lsB[cur][(wn * 64 + n * 16 + l15) * 64 + ((quad ^ rswz) << 3)];
#pragma unroll
    for (int m = 0; m < 8; ++m)
      af[m] = *(const bf16x8*)
          &lsA[cur][(wm * 128 + m * 16 + l15) * 64 + ((quad ^ rswz) << 3)];
    __builtin_amdgcn_s_setprio(1);
#pragma unroll
    for (int m = 0; m < 8; ++m)
#pragma unroll
      for (int n = 0; n < 4; ++n)
        acc[m][n] = __builtin_amdgcn_mfma_f32_16x16x32_bf16(
            af[m], bfv[n], acc[m][n], 0, 0, 0);
    __builtin_amdgcn_s_setprio(0);
    if (t < KT - 1) GSTAGE_B(t + 1, cur ^ 1);   // issue mid-tile (<=8 in flight)
    BARRIER();                    // lockstep between phases

    // ---- phase 1: ks = 1 ----
#pragma unroll
    for (int n = 0; n < 4; ++n)
      bfv[n] = *(const bf16x8*)
          &lsB[cur][(wn * 64 + n * 16 + l15) * 64 + (((4 + quad) ^ rswz) << 3)];
#pragma unroll
    for (int m = 0; m < 8; ++m)
      af[m] = *(const bf16x8*)
          &lsA[cur][(wm * 128 + m * 16 + l15) * 64 + (((4 + quad) ^ rswz) << 3)];
    __builtin_amdgcn_s_setprio(1);
#pragma unroll
    for (int m = 0; m < 8; ++m)
#pragma unroll
      for (int n = 0; n < 4; ++n)
        acc[m][n] = __builtin_amdgcn_mfma_f32_16x16x32_bf16(
            af[m], bfv[n], acc[m][n], 0, 0, 0);
    __builtin_amdgcn_s_setprio(0);
    BARRIER();                    // tile end: buf[cur] safe to re-stage next t
  }
#undef GSTAGE_A
#undef GSTAGE_B

  // Epilogue. C/D layout: col = lane&15, row = quad*4 + r (verified m89/m91).
#pragma unroll
  for (int i = 0; i < 8; ++i) {
#pragma unroll
    for (int j = 0; j < 4; ++j) {
      const int colb = n0 + wn * 64 + j * 16 + l15;
      const float bv = bias[colb];
      float vals[4];
#pragma unroll
      for (int r = 0; r < 4; ++r) vals[r] = acc[i][j][r] + bv;
      const int row0 = m0 + wm * 128 + i * 16 + quad * 4;
      if (MODE == 0) {
        const int b = row0 >> 11, t0 = row0 & (Tsz - 1);
        const int region = colb >> 10;        // 0:q 1:k 2:v (block-uniform)
        const int nc = colb & (Csz - 1);
        const int h = nc >> 6, d = nc & 63;
        if (region == 2) {
          // V transposed: [bh][d][t]; 4 consecutive t -> one 8B store.
          uint2 st;
          st.x = pack2bf(vals[0], vals[1]);
          st.y = pack2bf(vals[2], vals[3]);
          *(uint2*)&o2[((size_t)((b << 4) + h) * Dh + d) * Tsz + t0] = st;
        } else {
          u16* dst = (region == 0) ? o0 : o1;
          const float qs = (region == 0) ? SCL2 : 1.0f;  // fold softmax scale
#pragma unroll
          for (int r = 0; r < 4; ++r)
            dst[(size_t)(((b << 4) + h) * Tsz + t0 + r) * Dh + d] =
                f2bf(vals[r] * qs);
        }
      } else {
#pragma unroll
        for (int r = 0; r < 4; ++r)
          fout[(size_t)(row0 + r) * N + colb] = vals[r];
      }
    }
  }
}

// ---------------------------------------------------------------------------
// Fused causal flash attention (unchanged from round 2): static-max softmax,
// sequential paired q-tiles, XOR-swizzled LDS + global_load_lds staging,
// counted vmcnt(4) + raw barriers, setprio around MFMA.
// grid (bh=64, y=16), 256 threads; block handles jq=31-y then jq=y.
// ---------------------------------------------------------------------------
__global__ __launch_bounds__(256)
void attn_fused(const u16* __restrict__ qb, const u16* __restrict__ kbuf,
                const u16* __restrict__ vT, u16* __restrict__ outp) {
  __shared__ u16 Kl[2][64 * 64];   // [buf][key][d],  chunk-swizzled content
  __shared__ u16 Vt[2][64 * 64];   // [buf][d][key],  chunk-swizzled content
  const int tid = threadIdx.x, lane = tid & 63, w = tid >> 6;
  const int quad = lane >> 4, l15 = lane & 15;
  const int cswz = (l15 & 7) << 3;        // read-side XOR swizzle (u16 units)
  const int bh = blockIdx.x;
  const int b = bh >> 4, h = bh & 15;
  const u16* Q   = qb   + (size_t)bh * Tsz * Dh;
  const u16* Kg  = kbuf + (size_t)bh * Tsz * Dh;
  const u16* VTg = vT   + (size_t)bh * Dh * Tsz;

  const int srow   = lane >> 3;
  const int schunk = ((lane & 7) ^ srow) << 3;       // u16 offset in row
  const u16* gK0 = Kg  + (size_t)(w * 16 + srow) * Dh  + schunk;
  const u16* gV0 = VTg + (size_t)(w * 16 + srow) * Tsz + schunk;

#if __has_builtin(__builtin_amdgcn_global_load_lds)
#define STAGE(jj, bb) do {                                                     \
    const size_t kb_ = (size_t)(jj) * 64;                                      \
    _Pragma("unroll")                                                          \
    for (int i_ = 0; i_ < 2; ++i_) {                                           \
      __builtin_amdgcn_global_load_lds(                                        \
        (const __attribute__((address_space(1))) void*)(gK0 + (kb_ + (size_t)i_ * 8) * Dh), \
        (__attribute__((address_space(3))) void*)(&Kl[bb][(w * 16 + i_ * 8) * 64]), 16, 0, 0); \
      __builtin_amdgcn_global_load_lds(                                        \
        (const __attribute__((address_space(1))) void*)(gV0 + (size_t)(i_ * 8) * Tsz + kb_), \
        (__attribute__((address_space(3))) void*)(&Vt[bb][(w * 16 + i_ * 8) * 64]), 16, 0, 0); \
    }                                                                          \
  } while (0)
#else
#define STAGE(jj, bb) do {                                                     \
    const int kb_ = (jj) * 64;                                                 \
    _Pragma("unroll")                                                          \
    for (int cc_ = 0; cc_ < 2; ++cc_) {                                        \
      const int c_ = tid + cc_ * 256;                                          \
      const int rr_ = c_ >> 3, off_ = c_ & 7;                                  \
      const int dc_ = (off_ ^ (rr_ & 7)) << 3;                                 \
      *(uint4*)&Kl[bb][rr_ * 64 + dc_] =                                       \
          *(const uint4*)&Kg[(size_t)(kb_ + rr_) * Dh + off_ * 8];             \
      *(uint4*)&Vt[bb][rr_ * 64 + dc_] =                                       \
          *(const uint4*)&VTg[(size_t)rr_ * Tsz + kb_ + off_ * 8];             \
    }                                                                          \
  } while (0)
#endif

  for (int ph = 0; ph < 2; ++ph) {
    const int jq = ph ? (int)blockIdx.y : 31 - (int)blockIdx.y;

    // Q fragment (B-operand of S^T): lane holds Q[q=l15][d=quad*8+j].
    const int qrow = jq * 64 + w * 16 + l15;   // this lane's q (global row)
    const bf16x8 bq0 = *(const bf16x8*)&Q[(size_t)qrow * Dh + quad * 8];
    const bf16x8 bq1 = *(const bf16x8*)&Q[(size_t)qrow * Dh + 32 + quad * 8];

    f32x4 O[4];    // O^T: col q = l15, row d = nb*16 + quad*4 + r
#pragma unroll
    for (int nb = 0; nb < 4; ++nb) O[nb] = (f32x4){0.f, 0.f, 0.f, 0.f};
    float l_i = 0.f;               // per-lane partial sum (16 keys/lane/tile)

    STAGE(0, 0);

    for (int j = 0; j <= jq; ++j) {
      const int cur = j & 1;
      if (j < jq) {
        STAGE(j + 1, cur ^ 1);   // prefetch next tile (async DMA)
        asm volatile("s_waitcnt vmcnt(4)" ::: "memory");  // cur landed; 4 fly
      } else {
        asm volatile("s_waitcnt vmcnt(0)" ::: "memory");
      }
      BARRIER();

      const int kb = j * 64;
      const bool diag = (j == jq);
      const int tmax = diag ? (w + 1) : 4;   // 16-key sub-tiles with any work
      const u16* KT = Kl[cur];
      const u16* VL = Vt[cur];

      // S^T: A = K fragment (m=key=16t+l15, k=d=quad*8+jj), B = Q fragment.
      f32x4 S[4];
#pragma unroll
      for (int t = 0; t < 4; ++t) S[t] = (f32x4){0.f, 0.f, 0.f, 0.f};
      __builtin_amdgcn_s_setprio(1);
#pragma unroll
      for (int t = 0; t < 4; ++t) {
        if (t < tmax) {
          bf16x8 ak = *(const bf16x8*)&KT[(t * 16 + l15) * 64 + ((quad * 8) ^ cswz)];
          S[t] = __builtin_amdgcn_mfma_f32_16x16x32_bf16(ak, bq0, S[t], 0, 0, 0);
          ak = *(const bf16x8*)&KT[(t * 16 + l15) * 64 + ((quad * 8 + 32) ^ cswz)];
          S[t] = __builtin_amdgcn_mfma_f32_16x16x32_bf16(ak, bq1, S[t], 0, 0, 0);
        }
      }
      __builtin_amdgcn_s_setprio(0);

      // p = exp2(s) directly (scale pre-folded into Q); masked -> 0.
      float p[4][4];
      if (diag) {
#pragma unroll
        for (int t = 0; t < 4; ++t) {
          const int key0 = kb + t * 16 + quad * 4;
#pragma unroll
          for (int r = 0; r < 4; ++r) {
            const float sv =
                (t < tmax && key0 + r <= qrow) ? S[t][r] : NEG_BIG;
            p[t][r] = fast_exp2(sv);
            l_i += p[t][r];
          }
        }
      } else {
#pragma unroll
        for (int t = 0; t < 4; ++t)
#pragma unroll
          for (int r = 0; r < 4; ++r) {
            p[t][r] = fast_exp2(S[t][r]);
            l_i += p[t][r];
          }
      }

      // PV chunk 0 (keys 0..31 = tiles 0,1): B-frag key pi(quad*8+jj).
      u32x4 pu;
      pu[0] = pack2bf_trunc(p[0][0], p[0][1]);
      pu[1] = pack2bf_trunc(p[0][2], p[0][3]);
      pu[2] = pack2bf_trunc(p[1][0], p[1][1]);
      pu[3] = pack2bf_trunc(p[1][2], p[1][3]);
      bf16x8 pb = __builtin_bit_cast(bf16x8, pu);
      __builtin_amdgcn_s_setprio(1);
#pragma unroll
      for (int nb = 0; nb < 4; ++nb) {
        const uint2 a0 = *(const uint2*)&VL[(nb * 16 + l15) * 64 + ((quad * 4) ^ cswz)];
        const uint2 a1 = *(const uint2*)&VL[(nb * 16 + l15) * 64 + ((quad * 4 + 16) ^ cswz)];
        const u32x4 au = {a0.x, a0.y, a1.x, a1.y};
        O[nb] = __builtin_amdgcn_mfma_f32_16x16x32_bf16(
            __builtin_bit_cast(bf16x8, au), pb, O[nb], 0, 0, 0);
      }
      __builtin_amdgcn_s_setprio(0);
      if (tmax > 2) {   // PV chunk 1 (keys 32..63 = tiles 2,3)
        pu[0] = pack2bf_trunc(p[2][0], p[2][1]);
        pu[1] = pack2bf_trunc(p[2][2], p[2][3]);
        pu[2] = pack2bf_trunc(p[3][0], p[3][1]);
        pu[3] = pack2bf_trunc(p[3][2], p[3][3]);
        pb = __builtin_bit_cast(bf16x8, pu);
        __builtin_amdgcn_s_setprio(1);
#pragma unroll
        for (int nb = 0; nb < 4; ++nb) {
          const uint2 a0 = *(const uint2*)&VL[(nb * 16 + l15) * 64 + ((quad * 4 + 32) ^ cswz)];
          const uint2 a1 = *(const uint2*)&VL[(nb * 16 + l15) * 64 + ((quad * 4 + 48) ^ cswz)];
          const u32x4 au = {a0.x, a0.y, a1.x, a1.y};
          O[nb] = __builtin_amdgcn_mfma_f32_16x16x32_bf16(
              __builtin_bit_cast(bf16x8, au), pb, O[nb], 0, 0, 0);
        }
        __builtin_amdgcn_s_setprio(0);
      }
      BARRIER();   // all waves done reading buf[cur] before it is re-staged
    }

    // One cross-lane l reduction for the whole phase, then write out.
    float lt = l_i + __shfl_xor(l_i, 16, 64);
    lt += __shfl_xor(lt, 32, 64);
    const float inv = 1.0f / lt;
#pragma unroll
    for (int nb = 0; nb < 4; ++nb) {
      uint2 st;
      st.x = pack2bf(O[nb][0] * inv, O[nb][1] * inv);
      st.y = pack2bf(O[nb][2] * inv, O[nb][3] * inv);
      *(uint2*)&outp[(size_t)(b * Tsz + qrow) * Csz + h * Dh + nb * 16 + quad * 4] = st;
    }
  }
#undef STAGE
}

// ---------------------------------------------------------------------------
extern "C" void kernel_launch(void* const* d_in, const int* in_sizes, int n_in,
                              void* d_out, int out_size, void* d_ws, size_t ws_size,
                              hipStream_t stream) {
  const float* x      = (const float*)d_in[0];   // [B,T,C] fp32
  const float* W_attn = (const float*)d_in[1];   // [C,3C]  fp32
  const float* b_attn = (const float*)d_in[2];   // [3C]    fp32
  const float* W_proj = (const float*)d_in[3];   // [C,C]   fp32
  const float* b_proj = (const float*)d_in[4];   // [C]     fp32
  float* out = (float*)d_out;                    // [B,T,C] fp32

  u16* ws   = (u16*)d_ws;
  u16* xbf  = ws;                                // [B,T,C] bf16
  u16* qbuf = xbf  + (size_t)Mrows * Csz;        // [bh][t][d] (pre-scaled)
  u16* kbuf = qbuf + (size_t)Mrows * Csz;        // [bh][t][d]
  u16* vbuf = kbuf + (size_t)Mrows * Csz;        // [bh][d][t]  (transposed!)
  u16* aout = vbuf + (size_t)Mrows * Csz;        // [B,T,C] bf16
  u16* WTa  = aout + (size_t)Mrows * Csz;        // [3C][C] bf16
  u16* WTp  = WTa  + (size_t)Csz * 3 * Csz;      // [C][C]  bf16

  prep<<<CVT_BLKS + TRA_BLKS + TRP_BLKS, 256, 0, stream>>>(
      x, xbf, W_attn, WTa, W_proj, WTp);
  gemm_bt<0><<<dim3(3 * Csz / 256, Mrows / 256), dim3(512), 0, stream>>>(
      xbf, WTa, b_attn, qbuf, kbuf, vbuf, nullptr, 3 * Csz);
  attn_fused<<<dim3(Bsz * Hn, Tsz / 128), 256, 0, stream>>>(
      qbuf, kbuf, vbuf, aout);
  gemm_bt<1><<<dim3(Csz / 256, Mrows / 256), dim3(512), 0, stream>>>(
      aout, WTp, b_proj, nullptr, nullptr, nullptr, out, Csz);
}

// Round 4
// 249.044 us; speedup vs baseline: 1.0660x; 1.0660x over previous
//
#include <hip/hip_runtime.h>
#include <cstdint>
#include <cstddef>

// Problem constants (B=4, T=2048, C=1024, H=16, D=64). I/O dtype: fp32.
#define Bsz   4
#define Tsz   2048
#define Csz   1024
#define Hn    16
#define Dh    64
#define Mrows 8192        // B*T
#define KD    1024        // K dim of both GEMMs (= C)

#define NEG_BIG (-1.0e30f)   // finite mask sentinel: exp2(NEG_BIG) flushes to 0
#define SCL2  0.18033688011112042f  // (1/sqrt(64)) * log2(e): folded into Q at
// the QKV epilogue. p = exp2(s) directly; uniform 2^bias cancels in sum(pv)/sum(p).

typedef unsigned short u16;
typedef __bf16  bf16x8 __attribute__((ext_vector_type(8)));
typedef __bf16  bf16x2 __attribute__((ext_vector_type(2)));
typedef float   f32x4  __attribute__((ext_vector_type(4)));
typedef unsigned int u32x4 __attribute__((ext_vector_type(4)));

// Raw barrier + compiler memory fences on both sides (no implicit vmcnt(0)
// drain -- that drain is the structural stall of __syncthreads pipelines).
#define BARRIER() do { asm volatile("" ::: "memory");                          \
                       __builtin_amdgcn_s_barrier();                           \
                       asm volatile("" ::: "memory"); } while (0)

__device__ __forceinline__ u16 f2bf(float f) {
  union { float f; unsigned int i; } v; v.f = f;
  unsigned int u = v.i;
  return (u16)((u + 0x7fffu + ((u >> 16) & 1u)) >> 16);   // RNE
}
// Pack two f32 -> two bf16 in one uint (low = a, high = b), RNE.
__device__ __forceinline__ unsigned int pack2bf(float a, float b) {
#if __has_builtin(__builtin_amdgcn_cvt_pk_bf16_f32)
  union { bf16x2 h; unsigned int u; } cv;
  cv.h = __builtin_amdgcn_cvt_pk_bf16_f32(a, b);
  return cv.u;
#else
  return (unsigned int)f2bf(a) | ((unsigned int)f2bf(b) << 16);
#endif
}
// Pack two f32 -> two bf16 by TRUNCATION via one v_perm_b32 (positive P only).
__device__ __forceinline__ unsigned int pack2bf_trunc(float lo, float hi) {
  return __builtin_amdgcn_perm(__builtin_bit_cast(unsigned int, hi),
                               __builtin_bit_cast(unsigned int, lo),
                               0x07060302u);
}
__device__ __forceinline__ float fast_exp2(float x) {
#if __has_builtin(__builtin_amdgcn_exp2f)
  return __builtin_amdgcn_exp2f(x);
#else
  return exp2f(x);
#endif
}

// ---------------------------------------------------------------------------
// Fused preprocessing (ONE launch): region 0 converts x to bf16; regions 1/2
// transpose+convert W_attn / W_proj.
// ---------------------------------------------------------------------------
#define CVT_BLKS  (Mrows * Csz / 4 / 256)   // 8192
#define TRA_BLKS  (48 * 16)                 // W_attn: [1024][3072] -> [3072][1024]
#define TRP_BLKS  (16 * 16)                 // W_proj: [1024][1024] -> [1024][1024]

__global__ __launch_bounds__(256)
void prep(const float* __restrict__ x, u16* __restrict__ xbf,
          const float* __restrict__ Wa, u16* __restrict__ WTa,
          const float* __restrict__ Wp, u16* __restrict__ WTp) {
  __shared__ u16 tile[64][65];
  int bid = blockIdx.x;
  const int tid = threadIdx.x;
  if (bid < CVT_BLKS) {
    const int i = bid * 256 + tid;
    const float4 v = ((const float4*)x)[i];
    uint2 o;
    o.x = pack2bf(v.x, v.y);
    o.y = pack2bf(v.z, v.w);
    ((uint2*)xbf)[i] = o;
    return;
  }
  bid -= CVT_BLKS;
  const float* in; u16* out; int cols, bx, by;
  if (bid < TRA_BLKS) {
    in = Wa; out = WTa; cols = 3 * Csz; bx = bid % 48; by = bid / 48;
  } else {
    bid -= TRA_BLKS;
    in = Wp; out = WTp; cols = Csz; bx = bid & 15; by = bid >> 4;
  }
  const int tc = bx * 64, tr = by * 64;
  const int xx = tid & 63, y0 = tid >> 6;
#pragma unroll
  for (int yy = 0; yy < 64; yy += 4) {
    int r = yy + y0;
    tile[r][xx] = f2bf(in[(size_t)(tr + r) * cols + tc + xx]);
  }
  __syncthreads();
#pragma unroll
  for (int yy = 0; yy < 64; yy += 4) {
    int r = yy + y0;
    out[(size_t)(tc + r) * Csz + tr + xx] = tile[xx][r];
  }
}

// ---------------------------------------------------------------------------
// GEMM C[M,N] = A[M,K] * BT[N,K]^T + bias[N], bf16 in, fp32 acc.
// V4: parametric tile <BM,BN,WM,WN>. Fixes round-3 regressions:
//   - TWO barriers per K-tile (was 3), single stage point at iteration top.
//   - All 8 DMA (A+B) issued into buf^1 BEFORE vmcnt(8): tile-t's 8 oldest
//     loads drain, tile-t+1's 8 stay in flight. Per-wave ledger: each wave
//     waits its OWN vmcnt before the barrier -> post-barrier the buffer is
//     globally complete. End-of-tile barrier protects buf reads vs re-stage.
//   - Quadrant-interleaved compute (read bfv+af_q0+af_q1 / mfma q0 / read q2 /
//     mfma q1 / read q3 / mfma q2 / mfma q3): compiler pipelines ds_read
//     latency under MFMAs via fine lgkmcnt. setprio(1) around MFMA clusters.
//   - XOR-swizzled LDS (chunk ^= row&7, pre-swizzled DMA source): 0 conflicts
//     (verified rounds 2-3).
// gemm<0>: 256x256, 512 thr, 8 waves (2Mx4N), wave tile 128x64 (44 FLOP/LDS-B).
// gemm<1>: 128x128, 256 thr, 4 waves (2Mx2N), 64 KB LDS -> 2 blocks/CU,
//          512 blocks all-resident (no tail).
// MODE 0: QKV epilogue -> q/k scatter [bh][t][d]; Q PRE-SCALED by SCL2;
//         V scatter TRANSPOSED [bh][d][t] (packed 8B stores).
// MODE 1: plain epilogue -> fp32 fout[row*N + col].
// ---------------------------------------------------------------------------
template<int BM, int BN, int WM, int WN, int MODE>
__global__ __launch_bounds__((BM / WM) * (BN / WN) * 64, 2)
void gemm_bt(const u16* __restrict__ A, const u16* __restrict__ BT,
             const float* __restrict__ bias, u16* __restrict__ o0,
             u16* __restrict__ o1, u16* __restrict__ o2,
             float* __restrict__ fout, int N) {
  constexpr int NWAVE   = (BM / WM) * (BN / WN);
  constexpr int WAVES_N = BN / WN;
  constexpr int MF_M    = WM / 16;      // 8 or 4
  constexpr int MF_N    = WN / 16;      // 4
  constexpr int MPQ     = MF_M / 4;     // m-frags per quadrant: 2 or 1
  constexpr int AI      = BM / 8 / NWAVE;   // A DMA instrs per wave (=4)
  constexpr int BI      = BN / 8 / NWAVE;   // B DMA instrs per wave (=4)

  __shared__ u16 lsA[2][BM * 64];   // [buf][row][64], chunk-swizzled content
  __shared__ u16 lsB[2][BN * 64];
  const int tid  = threadIdx.x;
  const int lane = tid & 63;
  const int wid  = tid >> 6;
  const int wm   = wid / WAVES_N, wn = wid % WAVES_N;
  const int quad = lane >> 4, l15 = lane & 15;
  const int rswz = l15 & 7;                 // read-side XOR (16B-chunk units)

  // Bijective XCD-aware swizzle (grid sizes 384 / 512, both % 8 == 0).
  int bx, by;
  {
    const int nwg  = gridDim.x * gridDim.y;
    const int orig = (int)blockIdx.y * gridDim.x + (int)blockIdx.x;
    const int cpx  = nwg >> 3;
    const int swz  = (orig & 7) * cpx + (orig >> 3);
    bx = swz % gridDim.x; by = swz / gridDim.x;
  }
  const int m0 = by * BM, n0 = bx * BN;

  f32x4 acc[MF_M][MF_N];
#pragma unroll
  for (int i = 0; i < MF_M; ++i)
#pragma unroll
    for (int j = 0; j < MF_N; ++j) acc[i][j] = (f32x4){0.f, 0.f, 0.f, 0.f};

  // Staging: wave w DMAs rows [w*32, w*32+32) of A and of B per K-tile.
  // Each instr covers 8 rows (row = 128B = 8 lanes x 16B). Lane l: local row
  // l>>3, source chunk (l&7)^(l>>3) -- inverse swizzle, so LDS[r][c] =
  // G[r][c ^ (r&7)] with a LINEAR global_load_lds dest.
  const int srow   = lane >> 3;
  const int schunk = (lane & 7) ^ srow;
  const u16* gA = A  + (size_t)(m0 + wid * (BM / NWAVE) + srow) * KD + schunk * 8;
  const u16* gB = BT + (size_t)(n0 + wid * (BN / NWAVE) + srow) * KD + schunk * 8;

  auto gstage = [&](int t, int bb) {
#if __has_builtin(__builtin_amdgcn_global_load_lds)
#pragma unroll
    for (int i = 0; i < AI; ++i)
      __builtin_amdgcn_global_load_lds(
          (const __attribute__((address_space(1))) void*)(gA + (size_t)i * 8 * KD + t * 64),
          (__attribute__((address_space(3))) void*)(&lsA[bb][(wid * (BM / NWAVE) + i * 8) * 64]),
          16, 0, 0);
#pragma unroll
    for (int i = 0; i < BI; ++i)
      __builtin_amdgcn_global_load_lds(
          (const __attribute__((address_space(1))) void*)(gB + (size_t)i * 8 * KD + t * 64),
          (__attribute__((address_space(3))) void*)(&lsB[bb][(wid * (BN / NWAVE) + i * 8) * 64]),
          16, 0, 0);
#else
#pragma unroll
    for (int cc = 0; cc < BM * 64 / 8 / (NWAVE * 64); ++cc) {
      const int c = tid + cc * NWAVE * 64;
      const int rr = c >> 3, off = c & 7;
      const int dc = (off ^ (rr & 7)) << 3;
      *(uint4*)&lsA[bb][rr * 64 + dc] =
          *(const uint4*)&A[(size_t)(m0 + rr) * KD + t * 64 + off * 8];
    }
#pragma unroll
    for (int cc = 0; cc < BN * 64 / 8 / (NWAVE * 64); ++cc) {
      const int c = tid + cc * NWAVE * 64;
      const int rr = c >> 3, off = c & 7;
      const int dc = (off ^ (rr & 7)) << 3;
      *(uint4*)&lsB[bb][rr * 64 + dc] =
          *(const uint4*)&BT[(size_t)(n0 + rr) * KD + t * 64 + off * 8];
    }
#endif
  };

  // Fragment-read / MFMA quadrant macros (literal q -> all indices constant).
  bf16x8 bfv[MF_N][2];
  bf16x8 afA[MPQ][2], afB[MPQ][2];
#define READ_BFV(curb)                                                         \
  _Pragma("unroll")                                                            \
  for (int n = 0; n < MF_N; ++n)                                               \
    _Pragma("unroll")                                                          \
    for (int ks = 0; ks < 2; ++ks)                                             \
      bfv[n][ks] = *(const bf16x8*)&lsB[curb][(wn * WN + n * 16 + l15) * 64 +  \
                                             (((ks * 4 + quad) ^ rswz) << 3)];
#define READ_AF(qc, dst, curb)                                                 \
  _Pragma("unroll")                                                            \
  for (int mi = 0; mi < MPQ; ++mi)                                             \
    _Pragma("unroll")                                                          \
    for (int ks = 0; ks < 2; ++ks)                                             \
      dst[mi][ks] = *(const bf16x8*)                                           \
          &lsA[curb][(wm * WM + ((qc) * MPQ + mi) * 16 + l15) * 64 +           \
                     (((ks * 4 + quad) ^ rswz) << 3)];
#define MFMA_Q(qc, src)                                                        \
  __builtin_amdgcn_s_setprio(1);                                               \
  _Pragma("unroll")                                                            \
  for (int mi = 0; mi < MPQ; ++mi)                                             \
    _Pragma("unroll")                                                          \
    for (int n = 0; n < MF_N; ++n)                                             \
      _Pragma("unroll")                                                        \
      for (int ks = 0; ks < 2; ++ks)                                           \
        acc[(qc) * MPQ + mi][n] = __builtin_amdgcn_mfma_f32_16x16x32_bf16(     \
            src[mi][ks], bfv[n][ks], acc[(qc) * MPQ + mi][n], 0, 0, 0);        \
  __builtin_amdgcn_s_setprio(0);

  gstage(0, 0);
  const int KT = KD / 64;   // 16
  for (int t = 0; t < KT; ++t) {
    const int cur = t & 1;
    if (t < KT - 1) {
      gstage(t + 1, cur ^ 1);   // 8 DMA for t+1 into the other buffer
      asm volatile("s_waitcnt vmcnt(8)" ::: "memory");  // tile t landed; 8 fly
    } else {
      asm volatile("s_waitcnt vmcnt(0)" ::: "memory");
    }
    BARRIER();   // buf[cur] globally complete; buf[cur^1] reads (prev tile) done

    READ_BFV(cur);
    READ_AF(0, afA, cur);
    READ_AF(1, afB, cur);
    MFMA_Q(0, afA);
    READ_AF(2, afA, cur);
    MFMA_Q(1, afB);
    READ_AF(3, afB, cur);
    MFMA_Q(2, afA);
    MFMA_Q(3, afB);

    BARRIER();   // all reads of buf[cur] done before iter t+1 re-stages it
  }
#undef READ_BFV
#undef READ_AF
#undef MFMA_Q

  // Epilogue. C/D layout: col = lane&15, row = quad*4 + r (verified m89/m91).
#pragma unroll
  for (int i = 0; i < MF_M; ++i) {
#pragma unroll
    for (int j = 0; j < MF_N; ++j) {
      const int colb = n0 + wn * WN + j * 16 + l15;
      const float bv = bias[colb];
      float vals[4];
#pragma unroll
      for (int r = 0; r < 4; ++r) vals[r] = acc[i][j][r] + bv;
      const int row0 = m0 + wm * WM + i * 16 + quad * 4;
      if (MODE == 0) {
        const int b = row0 >> 11, t0 = row0 & (Tsz - 1);
        const int region = colb >> 10;        // 0:q 1:k 2:v (block-uniform)
        const int nc = colb & (Csz - 1);
        const int h = nc >> 6, d = nc & 63;
        if (region == 2) {
          // V transposed: [bh][d][t]; 4 consecutive t -> one 8B store.
          uint2 st;
          st.x = pack2bf(vals[0], vals[1]);
          st.y = pack2bf(vals[2], vals[3]);
          *(uint2*)&o2[((size_t)((b << 4) + h) * Dh + d) * Tsz + t0] = st;
        } else {
          u16* dst = (region == 0) ? o0 : o1;
          const float qs = (region == 0) ? SCL2 : 1.0f;  // fold softmax scale
#pragma unroll
          for (int r = 0; r < 4; ++r)
            dst[(size_t)(((b << 4) + h) * Tsz + t0 + r) * Dh + d] =
                f2bf(vals[r] * qs);
        }
      } else {
#pragma unroll
        for (int r = 0; r < 4; ++r)
          fout[(size_t)(row0 + r) * N + colb] = vals[r];
      }
    }
  }
}

// ---------------------------------------------------------------------------
// Fused causal flash attention (frozen since round 2): static-max softmax,
// sequential paired q-tiles, XOR-swizzled LDS + global_load_lds staging,
// counted vmcnt(4) + raw barriers, setprio around MFMA.
// grid (bh=64, y=16), 256 threads; block handles jq=31-y then jq=y.
// ---------------------------------------------------------------------------
__global__ __launch_bounds__(256)
void attn_fused(const u16* __restrict__ qb, const u16* __restrict__ kbuf,
                const u16* __restrict__ vT, u16* __restrict__ outp) {
  __shared__ u16 Kl[2][64 * 64];   // [buf][key][d],  chunk-swizzled content
  __shared__ u16 Vt[2][64 * 64];   // [buf][d][key],  chunk-swizzled content
  const int tid = threadIdx.x, lane = tid & 63, w = tid >> 6;
  const int quad = lane >> 4, l15 = lane & 15;
  const int cswz = (l15 & 7) << 3;        // read-side XOR swizzle (u16 units)
  const int bh = blockIdx.x;
  const int b = bh >> 4, h = bh & 15;
  const u16* Q   = qb   + (size_t)bh * Tsz * Dh;
  const u16* Kg  = kbuf + (size_t)bh * Tsz * Dh;
  const u16* VTg = vT   + (size_t)bh * Dh * Tsz;

  const int srow   = lane >> 3;
  const int schunk = ((lane & 7) ^ srow) << 3;       // u16 offset in row
  const u16* gK0 = Kg  + (size_t)(w * 16 + srow) * Dh  + schunk;
  const u16* gV0 = VTg + (size_t)(w * 16 + srow) * Tsz + schunk;

#if __has_builtin(__builtin_amdgcn_global_load_lds)
#define STAGE(jj, bb) do {                                                     \
    const size_t kb_ = (size_t)(jj) * 64;                                      \
    _Pragma("unroll")                                                          \
    for (int i_ = 0; i_ < 2; ++i_) {                                           \
      __builtin_amdgcn_global_load_lds(                                        \
        (const __attribute__((address_space(1))) void*)(gK0 + (kb_ + (size_t)i_ * 8) * Dh), \
        (__attribute__((address_space(3))) void*)(&Kl[bb][(w * 16 + i_ * 8) * 64]), 16, 0, 0); \
      __builtin_amdgcn_global_load_lds(                                        \
        (const __attribute__((address_space(1))) void*)(gV0 + (size_t)(i_ * 8) * Tsz + kb_), \
        (__attribute__((address_space(3))) void*)(&Vt[bb][(w * 16 + i_ * 8) * 64]), 16, 0, 0); \
    }                                                                          \
  } while (0)
#else
#define STAGE(jj, bb) do {                                                     \
    const int kb_ = (jj) * 64;                                                 \
    _Pragma("unroll")                                                          \
    for (int cc_ = 0; cc_ < 2; ++cc_) {                                        \
      const int c_ = tid + cc_ * 256;                                          \
      const int rr_ = c_ >> 3, off_ = c_ & 7;                                  \
      const int dc_ = (off_ ^ (rr_ & 7)) << 3;                                 \
      *(uint4*)&Kl[bb][rr_ * 64 + dc_] =                                       \
          *(const uint4*)&Kg[(size_t)(kb_ + rr_) * Dh + off_ * 8];             \
      *(uint4*)&Vt[bb][rr_ * 64 + dc_] =                                       \
          *(const uint4*)&VTg[(size_t)rr_ * Tsz + kb_ + off_ * 8];             \
    }                                                                          \
  } while (0)
#endif

  for (int ph = 0; ph < 2; ++ph) {
    const int jq = ph ? (int)blockIdx.y : 31 - (int)blockIdx.y;

    // Q fragment (B-operand of S^T): lane holds Q[q=l15][d=quad*8+j].
    const int qrow = jq * 64 + w * 16 + l15;   // this lane's q (global row)
    const bf16x8 bq0 = *(const bf16x8*)&Q[(size_t)qrow * Dh + quad * 8];
    const bf16x8 bq1 = *(const bf16x8*)&Q[(size_t)qrow * Dh + 32 + quad * 8];

    f32x4 O[4];    // O^T: col q = l15, row d = nb*16 + quad*4 + r
#pragma unroll
    for (int nb = 0; nb < 4; ++nb) O[nb] = (f32x4){0.f, 0.f, 0.f, 0.f};
    float l_i = 0.f;               // per-lane partial sum (16 keys/lane/tile)

    STAGE(0, 0);

    for (int j = 0; j <= jq; ++j) {
      const int cur = j & 1;
      if (j < jq) {
        STAGE(j + 1, cur ^ 1);   // prefetch next tile (async DMA)
        asm volatile("s_waitcnt vmcnt(4)" ::: "memory");  // cur landed; 4 fly
      } else {
        asm volatile("s_waitcnt vmcnt(0)" ::: "memory");
      }
      BARRIER();

      const int kb = j * 64;
      const bool diag = (j == jq);
      const int tmax = diag ? (w + 1) : 4;   // 16-key sub-tiles with any work
      const u16* KT = Kl[cur];
      const u16* VL = Vt[cur];

      // S^T: A = K fragment (m=key=16t+l15, k=d=quad*8+jj), B = Q fragment.
      f32x4 S[4];
#pragma unroll
      for (int t = 0; t < 4; ++t) S[t] = (f32x4){0.f, 0.f, 0.f, 0.f};
      __builtin_amdgcn_s_setprio(1);
#pragma unroll
      for (int t = 0; t < 4; ++t) {
        if (t < tmax) {
          bf16x8 ak = *(const bf16x8*)&KT[(t * 16 + l15) * 64 + ((quad * 8) ^ cswz)];
          S[t] = __builtin_amdgcn_mfma_f32_16x16x32_bf16(ak, bq0, S[t], 0, 0, 0);
          ak = *(const bf16x8*)&KT[(t * 16 + l15) * 64 + ((quad * 8 + 32) ^ cswz)];
          S[t] = __builtin_amdgcn_mfma_f32_16x16x32_bf16(ak, bq1, S[t], 0, 0, 0);
        }
      }
      __builtin_amdgcn_s_setprio(0);

      // p = exp2(s) directly (scale pre-folded into Q); masked -> 0.
      float p[4][4];
      if (diag) {
#pragma unroll
        for (int t = 0; t < 4; ++t) {
          const int key0 = kb + t * 16 + quad * 4;
#pragma unroll
          for (int r = 0; r < 4; ++r) {
            const float sv =
                (t < tmax && key0 + r <= qrow) ? S[t][r] : NEG_BIG;
            p[t][r] = fast_exp2(sv);
            l_i += p[t][r];
          }
        }
      } else {
#pragma unroll
        for (int t = 0; t < 4; ++t)
#pragma unroll
          for (int r = 0; r < 4; ++r) {
            p[t][r] = fast_exp2(S[t][r]);
            l_i += p[t][r];
          }
      }

      // PV chunk 0 (keys 0..31 = tiles 0,1): B-frag key pi(quad*8+jj).
      u32x4 pu;
      pu[0] = pack2bf_trunc(p[0][0], p[0][1]);
      pu[1] = pack2bf_trunc(p[0][2], p[0][3]);
      pu[2] = pack2bf_trunc(p[1][0], p[1][1]);
      pu[3] = pack2bf_trunc(p[1][2], p[1][3]);
      bf16x8 pb = __builtin_bit_cast(bf16x8, pu);
      __builtin_amdgcn_s_setprio(1);
#pragma unroll
      for (int nb = 0; nb < 4; ++nb) {
        const uint2 a0 = *(const uint2*)&VL[(nb * 16 + l15) * 64 + ((quad * 4) ^ cswz)];
        const uint2 a1 = *(const uint2*)&VL[(nb * 16 + l15) * 64 + ((quad * 4 + 16) ^ cswz)];
        const u32x4 au = {a0.x, a0.y, a1.x, a1.y};
        O[nb] = __builtin_amdgcn_mfma_f32_16x16x32_bf16(
            __builtin_bit_cast(bf16x8, au), pb, O[nb], 0, 0, 0);
      }
      __builtin_amdgcn_s_setprio(0);
      if (tmax > 2) {   // PV chunk 1 (keys 32..63 = tiles 2,3)
        pu[0] = pack2bf_trunc(p[2][0], p[2][1]);
        pu[1] = pack2bf_trunc(p[2][2], p[2][3]);
        pu[2] = pack2bf_trunc(p[3][0], p[3][1]);
        pu[3] = pack2bf_trunc(p[3][2], p[3][3]);
        pb = __builtin_bit_cast(bf16x8, pu);
        __builtin_amdgcn_s_setprio(1);
#pragma unroll
        for (int nb = 0; nb < 4; ++nb) {
          const uint2 a0 = *(const uint2*)&VL[(nb * 16 + l15) * 64 + ((quad * 4 + 32) ^ cswz)];
          const uint2 a1 = *(const uint2*)&VL[(nb * 16 + l15) * 64 + ((quad * 4 + 48) ^ cswz)];
          const u32x4 au = {a0.x, a0.y, a1.x, a1.y};
          O[nb] = __builtin_amdgcn_mfma_f32_16x16x32_bf16(
              __builtin_bit_cast(bf16x8, au), pb, O[nb], 0, 0, 0);
        }
        __builtin_amdgcn_s_setprio(0);
      }
      BARRIER();   // all waves done reading buf[cur] before it is re-staged
    }

    // One cross-lane l reduction for the whole phase, then write out.
    float lt = l_i + __shfl_xor(l_i, 16, 64);
    lt += __shfl_xor(lt, 32, 64);
    const float inv = 1.0f / lt;
#pragma unroll
    for (int nb = 0; nb < 4; ++nb) {
      uint2 st;
      st.x = pack2bf(O[nb][0] * inv, O[nb][1] * inv);
      st.y = pack2bf(O[nb][2] * inv, O[nb][3] * inv);
      *(uint2*)&outp[(size_t)(b * Tsz + qrow) * Csz + h * Dh + nb * 16 + quad * 4] = st;
    }
  }
#undef STAGE
}

// ---------------------------------------------------------------------------
extern "C" void kernel_launch(void* const* d_in, const int* in_sizes, int n_in,
                              void* d_out, int out_size, void* d_ws, size_t ws_size,
                              hipStream_t stream) {
  const float* x      = (const float*)d_in[0];   // [B,T,C] fp32
  const float* W_attn = (const float*)d_in[1];   // [C,3C]  fp32
  const float* b_attn = (const float*)d_in[2];   // [3C]    fp32
  const float* W_proj = (const float*)d_in[3];   // [C,C]   fp32
  const float* b_proj = (const float*)d_in[4];   // [C]     fp32
  float* out = (float*)d_out;                    // [B,T,C] fp32

  u16* ws   = (u16*)d_ws;
  u16* xbf  = ws;                                // [B,T,C] bf16
  u16* qbuf = xbf  + (size_t)Mrows * Csz;        // [bh][t][d] (pre-scaled)
  u16* kbuf = qbuf + (size_t)Mrows * Csz;        // [bh][t][d]
  u16* vbuf = kbuf + (size_t)Mrows * Csz;        // [bh][d][t]  (transposed!)
  u16* aout = vbuf + (size_t)Mrows * Csz;        // [B,T,C] bf16
  u16* WTa  = aout + (size_t)Mrows * Csz;        // [3C][C] bf16
  u16* WTp  = WTa  + (size_t)Csz * 3 * Csz;      // [C][C]  bf16

  prep<<<CVT_BLKS + TRA_BLKS + TRP_BLKS, 256, 0, stream>>>(
      x, xbf, W_attn, WTa, W_proj, WTp);
  // 256x256 tile, 512 thr: grid 12x32 = 384 blocks.
  gemm_bt<256, 256, 128, 64, 0><<<dim3(3 * Csz / 256, Mrows / 256),
                                  dim3(512), 0, stream>>>(
      xbf, WTa, b_attn, qbuf, kbuf, vbuf, nullptr, 3 * Csz);
  attn_fused<<<dim3(Bsz * Hn, Tsz / 128), 256, 0, stream>>>(
      qbuf, kbuf, vbuf, aout);
  // 128x128 tile, 256 thr: grid 8x64 = 512 blocks, 2/CU, all resident.
  gemm_bt<128, 128, 64, 64, 1><<<dim3(Csz / 128, Mrows / 128),
                                 dim3(256), 0, stream>>>(
      aout, WTp, b_proj, nullptr, nullptr, nullptr, out, Csz);
}

// Round 5
// 244.013 us; speedup vs baseline: 1.0880x; 1.0206x over previous
//
#include <hip/hip_runtime.h>
#include <cstdint>
#include <cstddef>

// Problem constants (B=4, T=2048, C=1024, H=16, D=64). I/O dtype: fp32.
#define Bsz   4
#define Tsz   2048
#define Csz   1024
#define Hn    16
#define Dh    64
#define Mrows 8192        // B*T
#define KD    1024        // K dim of both GEMMs (= C)

#define NEG_BIG (-1.0e30f)   // finite mask sentinel: exp2(NEG_BIG) flushes to 0
#define SCL2  0.18033688011112042f  // (1/sqrt(64)) * log2(e): folded into Q at
// the QKV epilogue. p = exp2(s) directly; uniform 2^bias cancels in sum(pv)/sum(p).

typedef unsigned short u16;
typedef __bf16  bf16x8 __attribute__((ext_vector_type(8)));
typedef __bf16  bf16x2 __attribute__((ext_vector_type(2)));
typedef float   f32x4  __attribute__((ext_vector_type(4)));
typedef unsigned int u32x4 __attribute__((ext_vector_type(4)));

// Raw barrier + compiler memory fences on both sides (no implicit vmcnt(0)
// drain -- that drain is the structural stall of __syncthreads pipelines).
#define BARRIER() do { asm volatile("" ::: "memory");                          \
                       __builtin_amdgcn_s_barrier();                           \
                       asm volatile("" ::: "memory"); } while (0)

__device__ __forceinline__ u16 f2bf(float f) {
  union { float f; unsigned int i; } v; v.f = f;
  unsigned int u = v.i;
  return (u16)((u + 0x7fffu + ((u >> 16) & 1u)) >> 16);   // RNE
}
// Pack two f32 -> two bf16 in one uint (low = a, high = b), RNE.
__device__ __forceinline__ unsigned int pack2bf(float a, float b) {
#if __has_builtin(__builtin_amdgcn_cvt_pk_bf16_f32)
  union { bf16x2 h; unsigned int u; } cv;
  cv.h = __builtin_amdgcn_cvt_pk_bf16_f32(a, b);
  return cv.u;
#else
  return (unsigned int)f2bf(a) | ((unsigned int)f2bf(b) << 16);
#endif
}
// Pack two f32 -> two bf16 by TRUNCATION via one v_perm_b32 (positive P only).
__device__ __forceinline__ unsigned int pack2bf_trunc(float lo, float hi) {
  return __builtin_amdgcn_perm(__builtin_bit_cast(unsigned int, hi),
                               __builtin_bit_cast(unsigned int, lo),
                               0x07060302u);
}
__device__ __forceinline__ float fast_exp2(float x) {
#if __has_builtin(__builtin_amdgcn_exp2f)
  return __builtin_amdgcn_exp2f(x);
#else
  return exp2f(x);
#endif
}

// ---------------------------------------------------------------------------
// Fused preprocessing (ONE launch): region 0 converts x to bf16; regions 1/2
// transpose+convert W_attn / W_proj.
// ---------------------------------------------------------------------------
#define CVT_BLKS  (Mrows * Csz / 4 / 256)   // 8192
#define TRA_BLKS  (48 * 16)                 // W_attn: [1024][3072] -> [3072][1024]
#define TRP_BLKS  (16 * 16)                 // W_proj: [1024][1024] -> [1024][1024]

__global__ __launch_bounds__(256)
void prep(const float* __restrict__ x, u16* __restrict__ xbf,
          const float* __restrict__ Wa, u16* __restrict__ WTa,
          const float* __restrict__ Wp, u16* __restrict__ WTp) {
  __shared__ u16 tile[64][65];
  int bid = blockIdx.x;
  const int tid = threadIdx.x;
  if (bid < CVT_BLKS) {
    const int i = bid * 256 + tid;
    const float4 v = ((const float4*)x)[i];
    uint2 o;
    o.x = pack2bf(v.x, v.y);
    o.y = pack2bf(v.z, v.w);
    ((uint2*)xbf)[i] = o;
    return;
  }
  bid -= CVT_BLKS;
  const float* in; u16* out; int cols, bx, by;
  if (bid < TRA_BLKS) {
    in = Wa; out = WTa; cols = 3 * Csz; bx = bid % 48; by = bid / 48;
  } else {
    bid -= TRA_BLKS;
    in = Wp; out = WTp; cols = Csz; bx = bid & 15; by = bid >> 4;
  }
  const int tc = bx * 64, tr = by * 64;
  const int xx = tid & 63, y0 = tid >> 6;
#pragma unroll
  for (int yy = 0; yy < 64; yy += 4) {
    int r = yy + y0;
    tile[r][xx] = f2bf(in[(size_t)(tr + r) * cols + tc + xx]);
  }
  __syncthreads();
#pragma unroll
  for (int yy = 0; yy < 64; yy += 4) {
    int r = yy + y0;
    out[(size_t)(tc + r) * Csz + tr + xx] = tile[xx][r];
  }
}

// ---------------------------------------------------------------------------
// GEMM C[M,N] = A[M,K] * BT[N,K]^T + bias[N], bf16 in, fp32 acc.
// V5: 128x128 tile, BK=32, 256 thr (4 waves 2x2, wave tile 64x64), LDS only
// 32 KiB (2buf x (A+B) x 128x32x2B) -> 4 blocks/CU. Rationale: round-4 proved
// the 2-phase schedule has a ~600 TF single-block ceiling (m233: stall =
// stage+vmcnt+barrier); at 1 block/CU nothing fills the bubbles. 4 resident
// blocks mutually hide each other's barrier stalls (TLP, not deeper SWP).
//   - counted s_waitcnt vmcnt(4): per-wave ledger -- after issuing tile t+1's
//     4 DMA, 8 outstanding; wait->4 means tile t landed, t+1 stays in flight.
//   - 2 raw barriers per K-tile (no implicit vmcnt(0) drain).
//   - 4-slot XOR swizzle for BK=32: LDS[r][slot] = G[r][slot ^ ((r>>1)&3)]
//     (16B slots). 16-lane read groups then alias max 2-way = free (m136).
//     DMA source pre-applies the inverse; LDS dest stays linear (rule #21).
//   - quadrant-interleaved reads/MFMAs + setprio(1) around MFMA clusters.
//   - bijective XCD swizzle (grids 1536 / 512, both % 8 == 0).
// MODE 0: QKV epilogue -> q/k scatter [bh][t][d]; Q PRE-SCALED by SCL2;
//         V scatter TRANSPOSED [bh][d][t] (packed 8B stores).
// MODE 1: plain epilogue -> fp32 fout[row*N + col].
// ---------------------------------------------------------------------------
template<int MODE>
__global__ __launch_bounds__(256, 4)
void gemm_bt(const u16* __restrict__ A, const u16* __restrict__ BT,
             const float* __restrict__ bias, u16* __restrict__ o0,
             u16* __restrict__ o1, u16* __restrict__ o2,
             float* __restrict__ fout, int N) {
  __shared__ u16 lsA[2][128 * 32];   // [buf][row][32], slot-swizzled content
  __shared__ u16 lsB[2][128 * 32];
  const int tid  = threadIdx.x;
  const int lane = tid & 63;
  const int wid  = tid >> 6;               // 0..3
  const int wm   = wid & 1, wn = wid >> 1; // wave tile 64x64
  const int quad = lane >> 4, l15 = lane & 15;
  const int rswz = (l15 >> 1) & 3;         // read-side XOR (16B-slot units)

  // Bijective XCD-aware swizzle (grid sizes 1536 / 512, both % 8 == 0).
  int bx, by;
  {
    const int nwg  = gridDim.x * gridDim.y;
    const int orig = (int)blockIdx.y * gridDim.x + (int)blockIdx.x;
    const int cpx  = nwg >> 3;
    const int swz  = (orig & 7) * cpx + (orig >> 3);
    bx = swz % gridDim.x; by = swz / gridDim.x;
  }
  const int m0 = by * 128, n0 = bx * 128;

  f32x4 acc[4][4];
#pragma unroll
  for (int i = 0; i < 4; ++i)
#pragma unroll
    for (int j = 0; j < 4; ++j) acc[i][j] = (f32x4){0.f, 0.f, 0.f, 0.f};

  // Staging: per K-tile, wave w DMAs A rows [w*32,w*32+32) and B rows same:
  // 2 instrs each (1 instr = 64 lanes x 16B = 16 rows of 64B). Lane l covers
  // row +(l>>2), slot l&3, with PRE-SWIZZLED source chunk (l&3)^((l>>3)&3)
  // so that LDS[r][s] = G[r][s ^ ((r>>1)&3)] with a LINEAR DMA dest.
  const int srow   = lane >> 2;
  const int schunk = (lane & 3) ^ ((lane >> 3) & 3);
  const u16* gA = A  + (size_t)(m0 + wid * 32 + srow) * KD + schunk * 8;
  const u16* gB = BT + (size_t)(n0 + wid * 32 + srow) * KD + schunk * 8;

  auto gstage = [&](int t, int bb) {
#if __has_builtin(__builtin_amdgcn_global_load_lds)
#pragma unroll
    for (int i = 0; i < 2; ++i)
      __builtin_amdgcn_global_load_lds(
          (const __attribute__((address_space(1))) void*)(gA + (size_t)i * 16 * KD + t * 32),
          (__attribute__((address_space(3))) void*)(&lsA[bb][(wid * 32 + i * 16) * 32]),
          16, 0, 0);
#pragma unroll
    for (int i = 0; i < 2; ++i)
      __builtin_amdgcn_global_load_lds(
          (const __attribute__((address_space(1))) void*)(gB + (size_t)i * 16 * KD + t * 32),
          (__attribute__((address_space(3))) void*)(&lsB[bb][(wid * 32 + i * 16) * 32]),
          16, 0, 0);
#else
#pragma unroll
    for (int cc = 0; cc < 2; ++cc) {
      const int c = tid + cc * 256;
      const int rr = c >> 2, off = c & 3;
      const int dc = (off ^ ((rr >> 1) & 3)) << 3;
      *(uint4*)&lsA[bb][rr * 32 + dc] =
          *(const uint4*)&A[(size_t)(m0 + rr) * KD + t * 32 + off * 8];
    }
#pragma unroll
    for (int cc = 0; cc < 2; ++cc) {
      const int c = tid + cc * 256;
      const int rr = c >> 2, off = c & 3;
      const int dc = (off ^ ((rr >> 1) & 3)) << 3;
      *(uint4*)&lsB[bb][rr * 32 + dc] =
          *(const uint4*)&BT[(size_t)(n0 + rr) * KD + t * 32 + off * 8];
    }
#endif
  };

  // Fragment read helpers. Row within tile: base + m*16 + l15; swizzle term
  // depends only on l15 (base and m*16 contribute multiples of 8 to row>>1).
#define READ_B(n_) (*(const bf16x8*)                                           \
    &lsB[cur][(wn * 64 + (n_) * 16 + l15) * 32 + ((quad ^ rswz) << 3)])
#define READ_A(m_) (*(const bf16x8*)                                           \
    &lsA[cur][(wm * 64 + (m_) * 16 + l15) * 32 + ((quad ^ rswz) << 3)])
#define MFMA_ROW(m_, src)                                                      \
  __builtin_amdgcn_s_setprio(1);                                               \
  _Pragma("unroll")                                                            \
  for (int n = 0; n < 4; ++n)                                                  \
    acc[m_][n] = __builtin_amdgcn_mfma_f32_16x16x32_bf16(                      \
        src, bfv[n], acc[m_][n], 0, 0, 0);                                     \
  __builtin_amdgcn_s_setprio(0);

  gstage(0, 0);
  const int KT = KD / 32;   // 32
  for (int t = 0; t < KT; ++t) {
    const int cur = t & 1;
    if (t < KT - 1) {
      gstage(t + 1, cur ^ 1);   // 4 DMA for t+1 into the other buffer
      asm volatile("s_waitcnt vmcnt(4)" ::: "memory");  // tile t landed; 4 fly
    } else {
      asm volatile("s_waitcnt vmcnt(0)" ::: "memory");
    }
    BARRIER();   // buf[cur] globally complete; prev reads of buf[cur^1] done

    bf16x8 bfv[4];
#pragma unroll
    for (int n = 0; n < 4; ++n) bfv[n] = READ_B(n);
    bf16x8 afA = READ_A(0);
    bf16x8 afB = READ_A(1);
    MFMA_ROW(0, afA);
    afA = READ_A(2);
    MFMA_ROW(1, afB);
    afB = READ_A(3);
    MFMA_ROW(2, afA);
    MFMA_ROW(3, afB);

    BARRIER();   // all reads of buf[cur] done before iter t+1 re-stages it
  }
#undef READ_B
#undef READ_A
#undef MFMA_ROW

  // Epilogue. C/D layout: col = lane&15, row = quad*4 + r (verified m89/m91).
#pragma unroll
  for (int i = 0; i < 4; ++i) {
#pragma unroll
    for (int j = 0; j < 4; ++j) {
      const int colb = n0 + wn * 64 + j * 16 + l15;
      const float bv = bias[colb];
      float vals[4];
#pragma unroll
      for (int r = 0; r < 4; ++r) vals[r] = acc[i][j][r] + bv;
      const int row0 = m0 + wm * 64 + i * 16 + quad * 4;
      if (MODE == 0) {
        const int b = row0 >> 11, t0 = row0 & (Tsz - 1);
        const int region = colb >> 10;        // 0:q 1:k 2:v (block-uniform)
        const int nc = colb & (Csz - 1);
        const int h = nc >> 6, d = nc & 63;
        if (region == 2) {
          // V transposed: [bh][d][t]; 4 consecutive t -> one 8B store.
          uint2 st;
          st.x = pack2bf(vals[0], vals[1]);
          st.y = pack2bf(vals[2], vals[3]);
          *(uint2*)&o2[((size_t)((b << 4) + h) * Dh + d) * Tsz + t0] = st;
        } else {
          u16* dst = (region == 0) ? o0 : o1;
          const float qs = (region == 0) ? SCL2 : 1.0f;  // fold softmax scale
#pragma unroll
          for (int r = 0; r < 4; ++r)
            dst[(size_t)(((b << 4) + h) * Tsz + t0 + r) * Dh + d] =
                f2bf(vals[r] * qs);
        }
      } else {
#pragma unroll
        for (int r = 0; r < 4; ++r)
          fout[(size_t)(row0 + r) * N + colb] = vals[r];
      }
    }
  }
}

// ---------------------------------------------------------------------------
// Fused causal flash attention (frozen since round 2): static-max softmax,
// sequential paired q-tiles, XOR-swizzled LDS + global_load_lds staging,
// counted vmcnt(4) + raw barriers, setprio around MFMA.
// grid (bh=64, y=16), 256 threads; block handles jq=31-y then jq=y.
// ---------------------------------------------------------------------------
__global__ __launch_bounds__(256)
void attn_fused(const u16* __restrict__ qb, const u16* __restrict__ kbuf,
                const u16* __restrict__ vT, u16* __restrict__ outp) {
  __shared__ u16 Kl[2][64 * 64];   // [buf][key][d],  chunk-swizzled content
  __shared__ u16 Vt[2][64 * 64];   // [buf][d][key],  chunk-swizzled content
  const int tid = threadIdx.x, lane = tid & 63, w = tid >> 6;
  const int quad = lane >> 4, l15 = lane & 15;
  const int cswz = (l15 & 7) << 3;        // read-side XOR swizzle (u16 units)
  const int bh = blockIdx.x;
  const int b = bh >> 4, h = bh & 15;
  const u16* Q   = qb   + (size_t)bh * Tsz * Dh;
  const u16* Kg  = kbuf + (size_t)bh * Tsz * Dh;
  const u16* VTg = vT   + (size_t)bh * Dh * Tsz;

  const int srow   = lane >> 3;
  const int schunk = ((lane & 7) ^ srow) << 3;       // u16 offset in row
  const u16* gK0 = Kg  + (size_t)(w * 16 + srow) * Dh  + schunk;
  const u16* gV0 = VTg + (size_t)(w * 16 + srow) * Tsz + schunk;

#if __has_builtin(__builtin_amdgcn_global_load_lds)
#define STAGE(jj, bb) do {                                                     \
    const size_t kb_ = (size_t)(jj) * 64;                                      \
    _Pragma("unroll")                                                          \
    for (int i_ = 0; i_ < 2; ++i_) {                                           \
      __builtin_amdgcn_global_load_lds(                                        \
        (const __attribute__((address_space(1))) void*)(gK0 + (kb_ + (size_t)i_ * 8) * Dh), \
        (__attribute__((address_space(3))) void*)(&Kl[bb][(w * 16 + i_ * 8) * 64]), 16, 0, 0); \
      __builtin_amdgcn_global_load_lds(                                        \
        (const __attribute__((address_space(1))) void*)(gV0 + (size_t)(i_ * 8) * Tsz + kb_), \
        (__attribute__((address_space(3))) void*)(&Vt[bb][(w * 16 + i_ * 8) * 64]), 16, 0, 0); \
    }                                                                          \
  } while (0)
#else
#define STAGE(jj, bb) do {                                                     \
    const int kb_ = (jj) * 64;                                                 \
    _Pragma("unroll")                                                          \
    for (int cc_ = 0; cc_ < 2; ++cc_) {                                        \
      const int c_ = tid + cc_ * 256;                                          \
      const int rr_ = c_ >> 3, off_ = c_ & 7;                                  \
      const int dc_ = (off_ ^ (rr_ & 7)) << 3;                                 \
      *(uint4*)&Kl[bb][rr_ * 64 + dc_] =                                       \
          *(const uint4*)&Kg[(size_t)(kb_ + rr_) * Dh + off_ * 8];             \
      *(uint4*)&Vt[bb][rr_ * 64 + dc_] =                                       \
          *(const uint4*)&VTg[(size_t)rr_ * Tsz + kb_ + off_ * 8];             \
    }                                                                          \
  } while (0)
#endif

  for (int ph = 0; ph < 2; ++ph) {
    const int jq = ph ? (int)blockIdx.y : 31 - (int)blockIdx.y;

    // Q fragment (B-operand of S^T): lane holds Q[q=l15][d=quad*8+j].
    const int qrow = jq * 64 + w * 16 + l15;   // this lane's q (global row)
    const bf16x8 bq0 = *(const bf16x8*)&Q[(size_t)qrow * Dh + quad * 8];
    const bf16x8 bq1 = *(const bf16x8*)&Q[(size_t)qrow * Dh + 32 + quad * 8];

    f32x4 O[4];    // O^T: col q = l15, row d = nb*16 + quad*4 + r
#pragma unroll
    for (int nb = 0; nb < 4; ++nb) O[nb] = (f32x4){0.f, 0.f, 0.f, 0.f};
    float l_i = 0.f;               // per-lane partial sum (16 keys/lane/tile)

    STAGE(0, 0);

    for (int j = 0; j <= jq; ++j) {
      const int cur = j & 1;
      if (j < jq) {
        STAGE(j + 1, cur ^ 1);   // prefetch next tile (async DMA)
        asm volatile("s_waitcnt vmcnt(4)" ::: "memory");  // cur landed; 4 fly
      } else {
        asm volatile("s_waitcnt vmcnt(0)" ::: "memory");
      }
      BARRIER();

      const int kb = j * 64;
      const bool diag = (j == jq);
      const int tmax = diag ? (w + 1) : 4;   // 16-key sub-tiles with any work
      const u16* KT = Kl[cur];
      const u16* VL = Vt[cur];

      // S^T: A = K fragment (m=key=16t+l15, k=d=quad*8+jj), B = Q fragment.
      f32x4 S[4];
#pragma unroll
      for (int t = 0; t < 4; ++t) S[t] = (f32x4){0.f, 0.f, 0.f, 0.f};
      __builtin_amdgcn_s_setprio(1);
#pragma unroll
      for (int t = 0; t < 4; ++t) {
        if (t < tmax) {
          bf16x8 ak = *(const bf16x8*)&KT[(t * 16 + l15) * 64 + ((quad * 8) ^ cswz)];
          S[t] = __builtin_amdgcn_mfma_f32_16x16x32_bf16(ak, bq0, S[t], 0, 0, 0);
          ak = *(const bf16x8*)&KT[(t * 16 + l15) * 64 + ((quad * 8 + 32) ^ cswz)];
          S[t] = __builtin_amdgcn_mfma_f32_16x16x32_bf16(ak, bq1, S[t], 0, 0, 0);
        }
      }
      __builtin_amdgcn_s_setprio(0);

      // p = exp2(s) directly (scale pre-folded into Q); masked -> 0.
      float p[4][4];
      if (diag) {
#pragma unroll
        for (int t = 0; t < 4; ++t) {
          const int key0 = kb + t * 16 + quad * 4;
#pragma unroll
          for (int r = 0; r < 4; ++r) {
            const float sv =
                (t < tmax && key0 + r <= qrow) ? S[t][r] : NEG_BIG;
            p[t][r] = fast_exp2(sv);
            l_i += p[t][r];
          }
        }
      } else {
#pragma unroll
        for (int t = 0; t < 4; ++t)
#pragma unroll
          for (int r = 0; r < 4; ++r) {
            p[t][r] = fast_exp2(S[t][r]);
            l_i += p[t][r];
          }
      }

      // PV chunk 0 (keys 0..31 = tiles 0,1): B-frag key pi(quad*8+jj).
      u32x4 pu;
      pu[0] = pack2bf_trunc(p[0][0], p[0][1]);
      pu[1] = pack2bf_trunc(p[0][2], p[0][3]);
      pu[2] = pack2bf_trunc(p[1][0], p[1][1]);
      pu[3] = pack2bf_trunc(p[1][2], p[1][3]);
      bf16x8 pb = __builtin_bit_cast(bf16x8, pu);
      __builtin_amdgcn_s_setprio(1);
#pragma unroll
      for (int nb = 0; nb < 4; ++nb) {
        const uint2 a0 = *(const uint2*)&VL[(nb * 16 + l15) * 64 + ((quad * 4) ^ cswz)];
        const uint2 a1 = *(const uint2*)&VL[(nb * 16 + l15) * 64 + ((quad * 4 + 16) ^ cswz)];
        const u32x4 au = {a0.x, a0.y, a1.x, a1.y};
        O[nb] = __builtin_amdgcn_mfma_f32_16x16x32_bf16(
            __builtin_bit_cast(bf16x8, au), pb, O[nb], 0, 0, 0);
      }
      __builtin_amdgcn_s_setprio(0);
      if (tmax > 2) {   // PV chunk 1 (keys 32..63 = tiles 2,3)
        pu[0] = pack2bf_trunc(p[2][0], p[2][1]);
        pu[1] = pack2bf_trunc(p[2][2], p[2][3]);
        pu[2] = pack2bf_trunc(p[3][0], p[3][1]);
        pu[3] = pack2bf_trunc(p[3][2], p[3][3]);
        pb = __builtin_bit_cast(bf16x8, pu);
        __builtin_amdgcn_s_setprio(1);
#pragma unroll
        for (int nb = 0; nb < 4; ++nb) {
          const uint2 a0 = *(const uint2*)&VL[(nb * 16 + l15) * 64 + ((quad * 4 + 32) ^ cswz)];
          const uint2 a1 = *(const uint2*)&VL[(nb * 16 + l15) * 64 + ((quad * 4 + 48) ^ cswz)];
          const u32x4 au = {a0.x, a0.y, a1.x, a1.y};
          O[nb] = __builtin_amdgcn_mfma_f32_16x16x32_bf16(
              __builtin_bit_cast(bf16x8, au), pb, O[nb], 0, 0, 0);
        }
        __builtin_amdgcn_s_setprio(0);
      }
      BARRIER();   // all waves done reading buf[cur] before it is re-staged
    }

    // One cross-lane l reduction for the whole phase, then write out.
    float lt = l_i + __shfl_xor(l_i, 16, 64);
    lt += __shfl_xor(lt, 32, 64);
    const float inv = 1.0f / lt;
#pragma unroll
    for (int nb = 0; nb < 4; ++nb) {
      uint2 st;
      st.x = pack2bf(O[nb][0] * inv, O[nb][1] * inv);
      st.y = pack2bf(O[nb][2] * inv, O[nb][3] * inv);
      *(uint2*)&outp[(size_t)(b * Tsz + qrow) * Csz + h * Dh + nb * 16 + quad * 4] = st;
    }
  }
#undef STAGE
}

// ---------------------------------------------------------------------------
extern "C" void kernel_launch(void* const* d_in, const int* in_sizes, int n_in,
                              void* d_out, int out_size, void* d_ws, size_t ws_size,
                              hipStream_t stream) {
  const float* x      = (const float*)d_in[0];   // [B,T,C] fp32
  const float* W_attn = (const float*)d_in[1];   // [C,3C]  fp32
  const float* b_attn = (const float*)d_in[2];   // [3C]    fp32
  const float* W_proj = (const float*)d_in[3];   // [C,C]   fp32
  const float* b_proj = (const float*)d_in[4];   // [C]     fp32
  float* out = (float*)d_out;                    // [B,T,C] fp32

  u16* ws   = (u16*)d_ws;
  u16* xbf  = ws;                                // [B,T,C] bf16
  u16* qbuf = xbf  + (size_t)Mrows * Csz;        // [bh][t][d] (pre-scaled)
  u16* kbuf = qbuf + (size_t)Mrows * Csz;        // [bh][t][d]
  u16* vbuf = kbuf + (size_t)Mrows * Csz;        // [bh][d][t]  (transposed!)
  u16* aout = vbuf + (size_t)Mrows * Csz;        // [B,T,C] bf16
  u16* WTa  = aout + (size_t)Mrows * Csz;        // [3C][C] bf16
  u16* WTp  = WTa  + (size_t)Csz * 3 * Csz;      // [C][C]  bf16

  prep<<<CVT_BLKS + TRA_BLKS + TRP_BLKS, 256, 0, stream>>>(
      x, xbf, W_attn, WTa, W_proj, WTp);
  // 128x128 tile, 256 thr: grid 24x64 = 1536 blocks, 4/CU target.
  gemm_bt<0><<<dim3(3 * Csz / 128, Mrows / 128), dim3(256), 0, stream>>>(
      xbf, WTa, b_attn, qbuf, kbuf, vbuf, nullptr, 3 * Csz);
  attn_fused<<<dim3(Bsz * Hn, Tsz / 128), 256, 0, stream>>>(
      qbuf, kbuf, vbuf, aout);
  // 128x128 tile, 256 thr: grid 8x64 = 512 blocks, all resident.
  gemm_bt<1><<<dim3(Csz / 128, Mrows / 128), dim3(256), 0, stream>>>(
      aout, WTp, b_proj, nullptr, nullptr, nullptr, out, Csz);
}